// Round 2
// baseline (269.491 us; speedup 1.0000x reference)
//
#include <hip/hip_runtime.h>
#include <math.h>

// Problem constants (b=16, n=512, h=1024)
#define NB 16
#define SEQ 512
#define HID 1024
#define XDIM 128       // 2*HEAD_SIZE
#define NHEADS 12
#define NROWS (NB*SEQ) // 8192
#define NEG_BIG 1000000000000.0f
#define MTILE 16

typedef __bf16 bf16x8 __attribute__((ext_vector_type(8)));
typedef __bf16 bf16x4 __attribute__((ext_vector_type(4)));
typedef float  f32x4  __attribute__((ext_vector_type(4)));

// ---------------------------------------------------------------------------
// Prep: W1T[n][k] = bf16(W1[k][n])  (128 x 1024 bf16, B^T layout for MFMA)
// ---------------------------------------------------------------------------
__global__ __launch_bounds__(256) void egp_prep(
    const float* __restrict__ W1, __bf16* __restrict__ W1T)
{
    int idx = blockIdx.x * 256 + threadIdx.x;   // 16384 threads
    int n   = idx >> 7;                         // 0..127
    int k0  = (idx & 127) << 3;                 // 0..1016 step 8
    bf16x8 o;
    #pragma unroll
    for (int j = 0; j < 8; j++)
        o[j] = (__bf16)W1[(size_t)(k0 + j) * XDIM + n];
    *(bf16x8*)(W1T + (size_t)n * HID + k0) = o;
}

// ---------------------------------------------------------------------------
// Stage 1 v2: barrier-free GEMM. A-fragments loaded straight from global fp32
// (frag layout: row = lane&15, k = quad*8 + j within each 32-chunk) and
// converted in-register; B from pre-transposed bf16 W1T. No LDS staging of A,
// no per-chunk __syncthreads. One barrier before the RoPE/bias epilogue.
// bias output transposed to [24][8192] for coalesced stage2 staging.
// ---------------------------------------------------------------------------
__global__ __launch_bounds__(256) void egp_stage1(
    const float* __restrict__ inp,   // (8192, 1024) fp32
    const __bf16* __restrict__ W1T,  // (128, 1024) bf16
    const float* __restrict__ b1,    // (128)
    const float* __restrict__ W2,    // (128, 24)
    const float* __restrict__ b2,    // (24)
    __bf16* __restrict__ qw,         // (8192, 64) bf16 row-major
    __bf16* __restrict__ kw,         // (8192, 64) bf16 row-major
    float* __restrict__ biasT)       // (24, 8192)  (already /2)
{
    __shared__ float Xs[MTILE][132];     // x rows for RoPE + bias GEMM
    __shared__ float W2s[XDIM * 24];
    __shared__ float b2s[24];

    const int t    = threadIdx.x;
    const int row0 = blockIdx.x * MTILE;
    const int lane = t & 63;
    const int w    = t >> 6;        // wave 0..3 -> cols [32w, 32w+32)
    const int quad = lane >> 4;
    const int l16  = lane & 15;
    const int ncol0 = w * 32;

    for (int i = t; i < XDIM * 24; i += 256) W2s[i] = W2[i];
    if (t < 24) b2s[t] = b2[t];

    // A: row (m) = l16, k-offset = quad*8 within each 32-wide chunk
    const float*  arow  = inp + (size_t)(row0 + l16) * HID + quad * 8;
    const __bf16* brow0 = W1T + (size_t)(ncol0 + l16) * HID + quad * 8;
    const __bf16* brow1 = brow0 + (size_t)16 * HID;

    f32x4 acc0 = {0.f, 0.f, 0.f, 0.f};
    f32x4 acc1 = {0.f, 0.f, 0.f, 0.f};

    #pragma unroll 4
    for (int kc = 0; kc < HID; kc += 32) {
        float4 af0 = *(const float4*)(arow + kc);
        float4 af1 = *(const float4*)(arow + kc + 4);
        bf16x8 a;
        a[0] = (__bf16)af0.x; a[1] = (__bf16)af0.y;
        a[2] = (__bf16)af0.z; a[3] = (__bf16)af0.w;
        a[4] = (__bf16)af1.x; a[5] = (__bf16)af1.y;
        a[6] = (__bf16)af1.z; a[7] = (__bf16)af1.w;
        bf16x8 b0 = *(const bf16x8*)(brow0 + kc);
        bf16x8 b1f = *(const bf16x8*)(brow1 + kc);
        acc0 = __builtin_amdgcn_mfma_f32_16x16x32_bf16(a, b0,  acc0, 0, 0, 0);
        acc1 = __builtin_amdgcn_mfma_f32_16x16x32_bf16(a, b1f, acc1, 0, 0, 0);
    }

    // C/D layout: col = l16 (the W1T column), row = quad*4 + r (the m row)
    float b1v0 = b1[ncol0 + l16];
    float b1v1 = b1[ncol0 + 16 + l16];
    #pragma unroll
    for (int r = 0; r < 4; r++) {
        Xs[quad * 4 + r][ncol0 + l16]      = acc0[r] + b1v0;
        Xs[quad * 4 + r][ncol0 + 16 + l16] = acc1[r] + b1v1;
    }
    __syncthreads();

    // --- RoPE -> qw', kw' (bf16) ---
    const int tx = t & 15;
    const int r  = t >> 4;
    const float LOG1E4 = 9.210340371976184f;  // ln(10000)
    float inv0 = expf(-((float)(2 * tx)     * (1.0f / 32.0f)) * LOG1E4);
    float inv1 = expf(-((float)(2 * tx + 1) * (1.0f / 32.0f)) * LOG1E4);
    {
        int grow  = row0 + r;
        float pos = (float)(grow & (SEQ - 1));
        float x[8];
        #pragma unroll
        for (int j = 0; j < 8; j++) x[j] = Xs[r][tx * 8 + j];
        float s0 = sinf(pos * inv0), c0 = cosf(pos * inv0);
        float s1 = sinf(pos * inv1), c1 = cosf(pos * inv1);
        bf16x4 q4, k4;
        q4[0] = (__bf16)(x[0] * c0 - x[2] * s0);
        q4[1] = (__bf16)(x[2] * c0 + x[0] * s0);
        q4[2] = (__bf16)(x[4] * c1 - x[6] * s1);
        q4[3] = (__bf16)(x[6] * c1 + x[4] * s1);
        k4[0] = (__bf16)(x[1] * c0 - x[3] * s0);
        k4[1] = (__bf16)(x[3] * c0 + x[1] * s0);
        k4[2] = (__bf16)(x[5] * c1 - x[7] * s1);
        k4[3] = (__bf16)(x[7] * c1 + x[5] * s1);
        *(bf16x4*)(qw + (size_t)grow * 64 + tx * 4) = q4;
        *(bf16x4*)(kw + (size_t)grow * 64 + tx * 4) = k4;
    }

    // --- bias = (x@W2+b2)/2, stored transposed [24][8192] ---
    for (int o = t; o < MTILE * 24; o += 256) {
        int row = o / 24;
        int jj  = o - row * 24;
        float s = 0.0f;
        #pragma unroll
        for (int kk = 0; kk < XDIM; kk++)
            s += Xs[row][kk] * W2s[kk * 24 + jj];
        biasT[(size_t)jj * NROWS + row0 + row] = (s + b2s[jj]) * 0.5f;
    }
}

// ---------------------------------------------------------------------------
// Stage 2 v4: m-tile 16 x FULL n=512. QK via 16 MFMAs/wave; mask+scale folded
// at the C->LDS store. Write phase: col4 = t&127 is iteration-invariant, so
// the thread's 8 Vals float4s are hoisted to registers once and bEs is read
// once per head; stores are nontemporal (201 MB write-once stream, keep out
// of L2). Grid: (32 m-tiles, 16 batches), 256 threads.
// ---------------------------------------------------------------------------
__global__ __launch_bounds__(256) void egp_stage2(
    const __bf16* __restrict__ qw,    // (8192, 64) bf16
    const __bf16* __restrict__ kw,    // (8192, 64) bf16
    const float* __restrict__ biasT,  // (24, 8192)
    const float* __restrict__ am,     // (16, 512)
    float* __restrict__ out)          // (16, 12, 512, 512)
{
    __shared__ float Vals[MTILE][516];   // masked+scaled qk tile, ~33 KB
    __shared__ float bEs[NHEADS][512];   // 24 KB
    __shared__ float bOs[NHEADS][MTILE];
    __shared__ float amN[512];
    __shared__ float amM[MTILE];

    const int b  = blockIdx.y;
    const int m0 = blockIdx.x * MTILE;
    const int t  = threadIdx.x;
    const int lane = t & 63;
    const int w    = t >> 6;
    const int quad = lane >> 4;
    const int l16  = lane & 15;

    // --- stage LDS: masks + per-head biases (coalesced from biasT) ---
    if (t < 128)
        *(f32x4*)(&amN[t * 4]) = *(const f32x4*)(am + b * SEQ + t * 4);
    if (t < MTILE) amM[t] = am[b * SEQ + m0 + t];
    for (int o = t; o < NHEADS * MTILE; o += 256) {
        int h  = o >> 4;
        int mm = o & 15;
        bOs[h][mm] = biasT[(size_t)(2 * h + 1) * NROWS + b * SEQ + m0 + mm];
    }
    for (int o = t; o < NHEADS * 128; o += 256) {
        int h  = o >> 7;
        int n4 = o & 127;
        *(f32x4*)(&bEs[h][n4 * 4]) =
            *(const f32x4*)(biasT + (size_t)(2 * h) * NROWS + b * SEQ + n4 * 4);
    }

    // --- QK MFMA: wave w covers n-strips nt = 8w..8w+7 ---
    const __bf16* qbase = qw + ((size_t)(b * SEQ + m0 + l16)) * 64 + quad * 8;
    bf16x8 a0 = *(const bf16x8*)(qbase);
    bf16x8 a1 = *(const bf16x8*)(qbase + 32);

    f32x4 acc[8];
    #pragma unroll
    for (int u = 0; u < 8; u++) {
        int nt = w * 8 + u;
        const __bf16* kbase = kw + ((size_t)(b * SEQ + nt * 16 + l16)) * 64 + quad * 8;
        bf16x8 b0 = *(const bf16x8*)(kbase);
        bf16x8 b1f = *(const bf16x8*)(kbase + 32);
        f32x4 z = {0.f, 0.f, 0.f, 0.f};
        z = __builtin_amdgcn_mfma_f32_16x16x32_bf16(a0, b0,  z, 0, 0, 0);
        z = __builtin_amdgcn_mfma_f32_16x16x32_bf16(a1, b1f, z, 0, 0, 0);
        acc[u] = z;
    }

    __syncthreads();   // amN/amM/bEs/bOs staged by other waves now visible

    // --- fold scale + masks, store to LDS (C/D: col=l16, row=quad*4+r) ---
    #pragma unroll
    for (int u = 0; u < 8; u++) {
        int n = w * 128 + u * 16 + l16;
        float an = amN[n];
        #pragma unroll
        for (int r = 0; r < 4; r++) {
            int mloc = quad * 4 + r;
            int m    = m0 + mloc;
            float msk = (1.0f - amM[mloc] * an) * NEG_BIG
                      + ((n < m) ? NEG_BIG : 0.0f);
            Vals[mloc][n] = acc[u][r] * 0.125f - msk;
        }
    }
    __syncthreads();

    // --- write phase: col4 invariant across it; Vals hoisted to registers ---
    const int col4 = t & 127;       // float4 column, fixed for this thread
    const int r0   = t >> 7;        // row = r0 + 2*it
    f32x4 v[8];
    #pragma unroll
    for (int it = 0; it < 8; it++)
        v[it] = *(const f32x4*)(&Vals[r0 + 2 * it][col4 * 4]);

    float* obase = out + ((size_t)(b * NHEADS) * SEQ + m0) * SEQ + (size_t)t * 4;
    #pragma unroll
    for (int h = 0; h < NHEADS; h++) {
        f32x4 e = *(const f32x4*)(&bEs[h][col4 * 4]);
        float* hbase = obase + (size_t)h * SEQ * SEQ;
        #pragma unroll
        for (int it = 0; it < 8; it++) {
            float bo = bOs[h][r0 + 2 * it];
            f32x4 o4 = v[it] + e + bo;
            __builtin_nontemporal_store(o4, (f32x4*)(hbase + (size_t)it * 1024));
        }
    }
}

extern "C" void kernel_launch(void* const* d_in, const int* in_sizes, int n_in,
                              void* d_out, int out_size, void* d_ws, size_t ws_size,
                              hipStream_t stream) {
    const float* inp = (const float*)d_in[0];   // (16,512,1024)
    const float* am  = (const float*)d_in[1];   // (16,512)
    const float* W1  = (const float*)d_in[2];   // (1024,128)
    const float* b1  = (const float*)d_in[3];   // (128)
    const float* W2  = (const float*)d_in[4];   // (128,24)
    const float* b2  = (const float*)d_in[5];   // (24)
    float* out = (float*)d_out;

    // workspace: qw bf16 (1MB) | kw bf16 (1MB) | biasT f32 (768KB) | W1T (256KB)
    __bf16* qw   = (__bf16*)d_ws;
    __bf16* kw   = qw + (size_t)NROWS * 64;
    float*  bias = (float*)(kw + (size_t)NROWS * 64);
    __bf16* w1t  = (__bf16*)(bias + (size_t)NROWS * 24);

    egp_prep<<<64, 256, 0, stream>>>(W1, w1t);
    egp_stage1<<<NROWS / MTILE, 256, 0, stream>>>(inp, w1t, b1, W2, b2, qw, kw, bias);

    dim3 g2(SEQ / MTILE, NB);
    egp_stage2<<<g2, 256, 0, stream>>>(qw, kw, bias, am, out);
}

// Round 3
// 267.585 us; speedup vs baseline: 1.0071x; 1.0071x over previous
//
#include <hip/hip_runtime.h>
#include <math.h>

// Problem constants (b=16, n=512, h=1024)
#define NB 16
#define SEQ 512
#define HID 1024
#define XDIM 128       // 2*HEAD_SIZE
#define NHEADS 12
#define NROWS (NB*SEQ) // 8192
#define NEG_BIG 1000000000000.0f
#define MTILE 16

typedef __bf16 bf16x8 __attribute__((ext_vector_type(8)));
typedef __bf16 bf16x4 __attribute__((ext_vector_type(4)));
typedef float  f32x4  __attribute__((ext_vector_type(4)));

// ---------------------------------------------------------------------------
// Prep: W1T[n][k] = bf16(W1[k][n])  (128 x 1024 bf16, B^T layout for MFMA)
// ---------------------------------------------------------------------------
__global__ __launch_bounds__(256) void egp_prep(
    const float* __restrict__ W1, __bf16* __restrict__ W1T)
{
    int idx = blockIdx.x * 256 + threadIdx.x;   // 16384 threads
    int n   = idx >> 7;                         // 0..127
    int k0  = (idx & 127) << 3;                 // 0..1016 step 8
    bf16x8 o;
    #pragma unroll
    for (int j = 0; j < 8; j++)
        o[j] = (__bf16)W1[(size_t)(k0 + j) * XDIM + n];
    *(bf16x8*)(W1T + (size_t)n * HID + k0) = o;
}

// ---------------------------------------------------------------------------
// Stage 1 (unchanged from R2): barrier-free GEMM, A-frags straight from
// global fp32, B from pre-transposed bf16 W1T. One barrier before epilogue.
// bias output transposed to [24][8192].
// ---------------------------------------------------------------------------
__global__ __launch_bounds__(256) void egp_stage1(
    const float* __restrict__ inp,   // (8192, 1024) fp32
    const __bf16* __restrict__ W1T,  // (128, 1024) bf16
    const float* __restrict__ b1,    // (128)
    const float* __restrict__ W2,    // (128, 24)
    const float* __restrict__ b2,    // (24)
    __bf16* __restrict__ qw,         // (8192, 64) bf16 row-major
    __bf16* __restrict__ kw,         // (8192, 64) bf16 row-major
    float* __restrict__ biasT)       // (24, 8192)  (already /2)
{
    __shared__ float Xs[MTILE][132];     // x rows for RoPE + bias GEMM
    __shared__ float W2s[XDIM * 24];
    __shared__ float b2s[24];

    const int t    = threadIdx.x;
    const int row0 = blockIdx.x * MTILE;
    const int lane = t & 63;
    const int w    = t >> 6;        // wave 0..3 -> cols [32w, 32w+32)
    const int quad = lane >> 4;
    const int l16  = lane & 15;
    const int ncol0 = w * 32;

    for (int i = t; i < XDIM * 24; i += 256) W2s[i] = W2[i];
    if (t < 24) b2s[t] = b2[t];

    // A: row (m) = l16, k-offset = quad*8 within each 32-wide chunk
    const float*  arow  = inp + (size_t)(row0 + l16) * HID + quad * 8;
    const __bf16* brow0 = W1T + (size_t)(ncol0 + l16) * HID + quad * 8;
    const __bf16* brow1 = brow0 + (size_t)16 * HID;

    f32x4 acc0 = {0.f, 0.f, 0.f, 0.f};
    f32x4 acc1 = {0.f, 0.f, 0.f, 0.f};

    #pragma unroll 4
    for (int kc = 0; kc < HID; kc += 32) {
        float4 af0 = *(const float4*)(arow + kc);
        float4 af1 = *(const float4*)(arow + kc + 4);
        bf16x8 a;
        a[0] = (__bf16)af0.x; a[1] = (__bf16)af0.y;
        a[2] = (__bf16)af0.z; a[3] = (__bf16)af0.w;
        a[4] = (__bf16)af1.x; a[5] = (__bf16)af1.y;
        a[6] = (__bf16)af1.z; a[7] = (__bf16)af1.w;
        bf16x8 b0 = *(const bf16x8*)(brow0 + kc);
        bf16x8 b1f = *(const bf16x8*)(brow1 + kc);
        acc0 = __builtin_amdgcn_mfma_f32_16x16x32_bf16(a, b0,  acc0, 0, 0, 0);
        acc1 = __builtin_amdgcn_mfma_f32_16x16x32_bf16(a, b1f, acc1, 0, 0, 0);
    }

    // C/D layout: col = l16 (the W1T column), row = quad*4 + r (the m row)
    float b1v0 = b1[ncol0 + l16];
    float b1v1 = b1[ncol0 + 16 + l16];
    #pragma unroll
    for (int r = 0; r < 4; r++) {
        Xs[quad * 4 + r][ncol0 + l16]      = acc0[r] + b1v0;
        Xs[quad * 4 + r][ncol0 + 16 + l16] = acc1[r] + b1v1;
    }
    __syncthreads();

    // --- RoPE -> qw', kw' (bf16) ---
    const int tx = t & 15;
    const int r  = t >> 4;
    const float LOG1E4 = 9.210340371976184f;  // ln(10000)
    float inv0 = expf(-((float)(2 * tx)     * (1.0f / 32.0f)) * LOG1E4);
    float inv1 = expf(-((float)(2 * tx + 1) * (1.0f / 32.0f)) * LOG1E4);
    {
        int grow  = row0 + r;
        float pos = (float)(grow & (SEQ - 1));
        float x[8];
        #pragma unroll
        for (int j = 0; j < 8; j++) x[j] = Xs[r][tx * 8 + j];
        float s0 = sinf(pos * inv0), c0 = cosf(pos * inv0);
        float s1 = sinf(pos * inv1), c1 = cosf(pos * inv1);
        bf16x4 q4, k4;
        q4[0] = (__bf16)(x[0] * c0 - x[2] * s0);
        q4[1] = (__bf16)(x[2] * c0 + x[0] * s0);
        q4[2] = (__bf16)(x[4] * c1 - x[6] * s1);
        q4[3] = (__bf16)(x[6] * c1 + x[4] * s1);
        k4[0] = (__bf16)(x[1] * c0 - x[3] * s0);
        k4[1] = (__bf16)(x[3] * c0 + x[1] * s0);
        k4[2] = (__bf16)(x[5] * c1 - x[7] * s1);
        k4[3] = (__bf16)(x[7] * c1 + x[5] * s1);
        *(bf16x4*)(qw + (size_t)grow * 64 + tx * 4) = q4;
        *(bf16x4*)(kw + (size_t)grow * 64 + tx * 4) = k4;
    }

    // --- bias = (x@W2+b2)/2, stored transposed [24][8192] ---
    for (int o = t; o < MTILE * 24; o += 256) {
        int row = o / 24;
        int jj  = o - row * 24;
        float s = 0.0f;
        #pragma unroll
        for (int kk = 0; kk < XDIM; kk++)
            s += Xs[row][kk] * W2s[kk * 24 + jj];
        biasT[(size_t)jj * NROWS + row0 + row] = (s + b2s[jj]) * 0.5f;
    }
}

// ---------------------------------------------------------------------------
// Stage 2 v5: n-SPLIT. Grid (32 m-tiles, 16 batches, 2 n-halves), 256 thr.
// Each block owns a 16 x 256 tile of qk and 196 KB of output. LDS down to
// ~31 KB (was 57), acc regs halved -> 4+ blocks/CU instead of 2, doubling
// the number of independent NT-store streams per CU.
// ---------------------------------------------------------------------------
#define NHALF 256
__global__ __launch_bounds__(256) void egp_stage2(
    const __bf16* __restrict__ qw,    // (8192, 64) bf16
    const __bf16* __restrict__ kw,    // (8192, 64) bf16
    const float* __restrict__ biasT,  // (24, 8192)
    const float* __restrict__ am,     // (16, 512)
    float* __restrict__ out)          // (16, 12, 512, 512)
{
    __shared__ float Vals[MTILE][NHALF + 4];  // 16.6 KB
    __shared__ float bEs[NHEADS][NHALF];      // 12 KB
    __shared__ float bOs[NHEADS][MTILE];
    __shared__ float amN[NHALF];
    __shared__ float amM[MTILE];

    const int b  = blockIdx.y;
    const int m0 = blockIdx.x * MTILE;
    const int z  = blockIdx.z;           // n-half: cols z*256 .. z*256+255
    const int n0 = z * NHALF;
    const int t  = threadIdx.x;
    const int lane = t & 63;
    const int w    = t >> 6;
    const int quad = lane >> 4;
    const int l16  = lane & 15;

    // --- stage LDS: masks + per-head biases (coalesced from biasT) ---
    if (t < NHALF / 4)
        *(f32x4*)(&amN[t * 4]) = *(const f32x4*)(am + b * SEQ + n0 + t * 4);
    if (t < MTILE) amM[t] = am[b * SEQ + m0 + t];
    if (t < NHEADS * MTILE) {
        int h  = t >> 4;
        int mm = t & 15;
        bOs[h][mm] = biasT[(size_t)(2 * h + 1) * NROWS + b * SEQ + m0 + mm];
    }
    for (int o = t; o < NHEADS * (NHALF / 4); o += 256) {
        int h  = o >> 6;
        int n4 = o & 63;
        *(f32x4*)(&bEs[h][n4 * 4]) =
            *(const f32x4*)(biasT + (size_t)(2 * h) * NROWS + b * SEQ + n0 + n4 * 4);
    }

    // --- QK MFMA: wave w covers n-strips u = 0..3 (n_local = w*64+u*16+l16)
    const __bf16* qbase = qw + ((size_t)(b * SEQ + m0 + l16)) * 64 + quad * 8;
    bf16x8 a0 = *(const bf16x8*)(qbase);
    bf16x8 a1 = *(const bf16x8*)(qbase + 32);

    f32x4 acc[4];
    #pragma unroll
    for (int u = 0; u < 4; u++) {
        int nl = w * 64 + u * 16 + l16;
        const __bf16* kbase = kw + ((size_t)(b * SEQ + n0 + nl)) * 64 + quad * 8;
        bf16x8 b0 = *(const bf16x8*)(kbase);
        bf16x8 b1f = *(const bf16x8*)(kbase + 32);
        f32x4 zz = {0.f, 0.f, 0.f, 0.f};
        zz = __builtin_amdgcn_mfma_f32_16x16x32_bf16(a0, b0,  zz, 0, 0, 0);
        zz = __builtin_amdgcn_mfma_f32_16x16x32_bf16(a1, b1f, zz, 0, 0, 0);
        acc[u] = zz;
    }

    __syncthreads();   // amN/amM/bEs/bOs staged by other waves now visible

    // --- fold scale + masks, store to LDS (C/D: col=l16, row=quad*4+r) ---
    #pragma unroll
    for (int u = 0; u < 4; u++) {
        int nl = w * 64 + u * 16 + l16;
        int n  = n0 + nl;
        float an = amN[nl];
        #pragma unroll
        for (int r = 0; r < 4; r++) {
            int mloc = quad * 4 + r;
            int m    = m0 + mloc;
            float msk = (1.0f - amM[mloc] * an) * NEG_BIG
                      + ((n < m) ? NEG_BIG : 0.0f);
            Vals[mloc][nl] = acc[u][r] * 0.125f - msk;
        }
    }
    __syncthreads();

    // --- write phase: col4 = lane (fixed), rows w + 4*it ---
    const int col4 = t & 63;        // float4 column within the half
    const int r0   = t >> 6;        // = wave; row = r0 + 4*it
    f32x4 v[4];
    #pragma unroll
    for (int it = 0; it < 4; it++)
        v[it] = *(const f32x4*)(&Vals[r0 + 4 * it][col4 * 4]);

    float* obase = out + ((size_t)(b * NHEADS) * SEQ + m0 + r0) * SEQ
                 + n0 + (size_t)col4 * 4;
    #pragma unroll
    for (int h = 0; h < NHEADS; h++) {
        f32x4 e = *(const f32x4*)(&bEs[h][col4 * 4]);
        float* hbase = obase + (size_t)h * SEQ * SEQ;
        #pragma unroll
        for (int it = 0; it < 4; it++) {
            float bo = bOs[h][r0 + 4 * it];
            f32x4 o4 = v[it] + e + bo;
            __builtin_nontemporal_store(o4, (f32x4*)(hbase + (size_t)it * 4 * SEQ));
        }
    }
}

extern "C" void kernel_launch(void* const* d_in, const int* in_sizes, int n_in,
                              void* d_out, int out_size, void* d_ws, size_t ws_size,
                              hipStream_t stream) {
    const float* inp = (const float*)d_in[0];   // (16,512,1024)
    const float* am  = (const float*)d_in[1];   // (16,512)
    const float* W1  = (const float*)d_in[2];   // (1024,128)
    const float* b1  = (const float*)d_in[3];   // (128)
    const float* W2  = (const float*)d_in[4];   // (128,24)
    const float* b2  = (const float*)d_in[5];   // (24)
    float* out = (float*)d_out;

    // workspace: qw bf16 (1MB) | kw bf16 (1MB) | biasT f32 (768KB) | W1T (256KB)
    __bf16* qw   = (__bf16*)d_ws;
    __bf16* kw   = qw + (size_t)NROWS * 64;
    float*  bias = (float*)(kw + (size_t)NROWS * 64);
    __bf16* w1t  = (__bf16*)(bias + (size_t)NROWS * 24);

    egp_prep<<<64, 256, 0, stream>>>(W1, w1t);
    egp_stage1<<<NROWS / MTILE, 256, 0, stream>>>(inp, w1t, b1, W2, b2, qw, kw, bias);

    dim3 g2(SEQ / MTILE, NB, 2);
    egp_stage2<<<g2, 256, 0, stream>>>(qw, kw, bias, am, out);
}